// Round 17
// baseline (10090.125 us; speedup 1.0000x reference)
//
#include <hip/hip_runtime.h>
#include <math.h>

#define NSTATES 1024
#define TT      4096
#define DD      20

#define FW_BLOCKS  64
#define FW_THREADS 256
#define JPB  16      // j per block   (FW_BLOCKS * JPB = NSTATES)
#define NSEG 16      // k segments    (JPB * NSEG = FW_THREADS)
#define KSEG 64      // k per segment (NSEG * KSEG = NSTATES)

#define SENT 0x7FC00000u   // canonical NaN: computed column values are never NaN

// workspace layout (bytes)
//   ws + 0      : ctrl[4]   (u32: [0]=fw ready, [1]=map count, [2]=compose flag)
//   ws + 256    : entries[64] (u32 per-segment entry front)
//   ws + 4096   : maps[64][512] (u32-packed u16 exit maps, 128 KB)
#define OFF_COLS  ((size_t)20 << 20)        // 16 MB per-step columns cols[t*N+j]
#define OFF_PTR   ((size_t)36 << 20)        // 8 MB  u16 backpointers, rows 1..T-1

typedef unsigned int u32;
typedef u32 u32x4 __attribute__((ext_vector_type(4)));

#define ALD(p) __hip_atomic_load((p), __ATOMIC_RELAXED, __HIP_MEMORY_SCOPE_AGENT)
#define AST(p, v) __hip_atomic_store((p), (v), __ATOMIC_RELAXED, __HIP_MEMORY_SCOPE_AGENT)

// Forward pass: R15 verbatim except the poll's FIRST sweep of column t is
// issued (as 4 proven agent-scope ALD word loads into carried registers)
// right after this block publishes its slice of column t. barrier 3 is a
// fence, so the loads issue pre-barrier and their LLC RTT rides under the
// emis/d-sum shadow; loop top consumes the carried values with zero poll
// latency on hit. On miss, the R15-proven retry loop takes over unchanged.
// (R16's asm-carried variant of this idea hit a container failure; this
// formulation uses zero new asm -- only primitives verified in R3-R15.)
__global__ __launch_bounds__(FW_THREADS, 1) void k_forward(
    const float* __restrict__ tr, const float* __restrict__ ev,
    const float* __restrict__ epar, const float* __restrict__ prior,
    float* __restrict__ cols, unsigned short* __restrict__ bptr,
    u32* __restrict__ ready)
{
    // padded [16][68]: row r holds words [r*64, r*64+64) of the prev column.
    __shared__ __align__(16) float prevs[NSEG * 68];
    __shared__ float          smaxw[4][JPB];   // per-wave partials (segs 4w..4w+3)
    __shared__ unsigned short sidxw[4][JPB];
    __shared__ float          elp[2][JPB][DD]; // double-buffered emission log-p
    const int tid  = threadIdx.x;
    const int seg  = tid >> 4;                  // 0..15: k in [seg*64, seg*64+64)
    const int jj   = tid & (JPB - 1);
    const int wav  = tid >> 6;                  // wave id 0..3 (holds segs 4w..4w+3)
    const int j0   = blockIdx.x * JPB;
    const int j    = j0 + jj;

    // ---- prologue A: sentinel-fill this block's slice of cols (256 KB)
    {
        uint4* mine = (uint4*)cols + (size_t)blockIdx.x * (NSTATES * TT / 4 / FW_BLOCKS);
        const uint4 sv = make_uint4(SENT, SENT, SENT, SENT);
        #pragma unroll
        for (int i = 0; i < (NSTATES * TT / 4 / FW_BLOCKS) / FW_THREADS; ++i)
            mine[i * FW_THREADS + tid] = sv;
    }

    // ---- prologue B: lat slice direct from tr (bit-identical to k_logtrans:
    // same logf on the same tr element). lat[j*N+k] = logf(tr[k*N+j]).
    const float lat00 = logf(tr[0]);            // log trans[0][0] (j==0 quirk)
    float4 latr[16];
    #pragma unroll
    for (int u = 0; u < 16; ++u) {
        #pragma unroll
        for (int i = 0; i < 4; ++i) {
            int k = seg * KSEG + u * 4 + i;
            ((float*)&latr[u])[i] = logf(tr[(size_t)k * NSTATES + j]);
        }
    }

    // ---- distributed-emission constants (items: it0 = tid, it1 = tid+256);
    // item -> (jj_e = item/20, d_e = item%20); 320 items cover 16j x 20d.
    const int jj0e = tid / DD, d0e = tid % DD;
    const float m0 = epar[((size_t)(j0 + jj0e) * DD + d0e) * 2 + 0];
    const float s0 = epar[((size_t)(j0 + jj0e) * DD + d0e) * 2 + 1];
    const float coef0 = 1.0f / sqrtf(6.2831853071795864769f * s0);
    const float den0  = 2.0f * (s0 * s0);
    const bool  has1  = (tid + 256) < JPB * DD;     // tid < 64
    const int   it1   = tid + 256;
    const int jj1e = has1 ? it1 / DD : 0, d1e = has1 ? it1 % DD : 0;
    const float m1 = has1 ? epar[((size_t)(j0 + jj1e) * DD + d1e) * 2 + 0] : 0.0f;
    const float s1 = has1 ? epar[((size_t)(j0 + jj1e) * DD + d1e) * 2 + 1] : 1.0f;
    const float coef1 = 1.0f / sqrtf(6.2831853071795864769f * s1);
    const float den1  = 2.0f * (s1 * s1);

    // faithful to reference: p = coef * expf(-num/den); logp = logf(p).
    // -inf (underflow) propagates; never NaN. Verbatim from the verified k_emis.
    auto emis = [&](int t, int buf) {
        float x0  = ev[(size_t)t * DD + d0e];
        float df0 = x0 - m0;
        float num0 = df0 * df0;
        float p0  = coef0 * expf(-num0 / den0);
        elp[buf][jj0e][d0e] = logf(p0);
        if (has1) {
            float x1  = ev[(size_t)t * DD + d1e];
            float df1 = x1 - m1;
            float num1 = df1 * df1;
            float p1  = coef1 * expf(-num1 / den1);
            elp[buf][jj1e][d1e] = logf(p1);
        }
    };

    // ---- prologue C: grid-ready barrier (fill visible -> count -> spin)
    __syncthreads();                            // block's fill issued by all
    if (tid == 0) {
        asm volatile("s_waitcnt vmcnt(0)" ::: "memory");   // fill visible first
        __hip_atomic_fetch_add(ready, 1u, __ATOMIC_RELEASE,
                               __HIP_MEMORY_SCOPE_AGENT);
        while (ALD(ready) < (u32)FW_BLOCKS) __builtin_amdgcn_s_sleep(2);
    }
    __syncthreads();                            // whole grid sentinel-ready

    // thread stages its 4 polled words at padded (row tid>>4, col (tid&15)*4)
    float* dstp = &prevs[(tid >> 4) * 68 + (tid & 15) * 4];
    const float* rowp = &prevs[seg * 68];

    // ---- prologue D: col0 (t=0) and the pipelined esum for t=1 ----
    emis(0, 0);
    __syncthreads();
    if (tid < JPB) {
        float acc = 0.0f;
        #pragma unroll
        for (int d = 0; d < DD; ++d) acc += elp[0][tid][d];   // ascending d
        float c0 = logf(prior[j0 + tid]) + acc;
        AST((u32*)cols + (j0 + tid), __float_as_uint(c0));
    }
    __syncthreads();                            // col0 sum read before buf reuse

    // issue the first sweep of column 0 (consumed at t=1's loop top); its RTT
    // overlaps the emis(1)+d-sum below (barrier is a fence: no sinking).
    u32 pf0, pf1, pf2, pf3;
    {
        const u32* pn = (const u32*)cols + tid * 4;
        pf0 = ALD(pn + 0); pf1 = ALD(pn + 1); pf2 = ALD(pn + 2); pf3 = ALD(pn + 3);
    }
    emis(1, 1);
    __syncthreads();
    float esum_reg = 0.0f;
    if (tid < JPB) {
        #pragma unroll
        for (int d = 0; d < DD; ++d) esum_reg += elp[1][tid][d];   // ascending d
    }

    for (int t = 1; t < TT; ++t) {
        // ---- consume the prefetched sweep of column t-1 (issued in the
        // previous iteration's shadow / prologue). On miss, fall into the
        // R15-proven retry loop (fresh sc1 sweeps + sleep + ALD fallback).
        const u32* p = (const u32*)(cols + (size_t)(t - 1) * NSTATES) + tid * 4;
        u32x4 A;
        A.x = pf0; A.y = pf1; A.z = pf2; A.w = pf3;
        if (A.x == SENT || A.y == SENT || A.z == SENT || A.w == SENT) {
            int tries = 0;
            for (;;) {
                asm volatile(
                    "global_load_dwordx4 %0, %1, off sc1\n\t"
                    "s_waitcnt vmcnt(0)"
                    : "=&v"(A) : "v"(p) : "memory");
                if (A.x != SENT && A.y != SENT && A.z != SENT && A.w != SENT) break;
                if (++tries >= 32) {
                    u32 a0 = ALD(p + 0), a1 = ALD(p + 1), a2 = ALD(p + 2), a3 = ALD(p + 3);
                    if (a0 != SENT && a1 != SENT && a2 != SENT && a3 != SENT) {
                        A.x = a0; A.y = a1; A.z = a2; A.w = a3;
                        break;
                    }
                    tries = 0;
                }
                __builtin_amdgcn_s_sleep(1);
            }
        }
        {
            float4 v;
            v.x = __uint_as_float(A.x);
            v.y = __uint_as_float(A.y);
            v.z = __uint_as_float(A.z);
            v.w = __uint_as_float(A.w);
            *(float4*)dstp = v;                 // padded b128 store, conflict-free
        }
        // barrier 1 removed (R15): row r's stagers == row r's readers (same
        // wave); same-wave LDS pipe is in-order. Fence stops compiler hoisting
        // the dependent ds_reads above the staging write (rule #18).
        asm volatile("s_waitcnt lgkmcnt(0)" ::: "memory");
        __builtin_amdgcn_sched_barrier(0);

        // ---- scan this thread's 64 k's for its j: first-max (strict >, asc k)
        float best = -__builtin_inff();
        int bidx = seg * KSEG;
        #pragma unroll
        for (int u = 0; u < 16; ++u) {
            float4 q  = *(const float4*)(rowp + u * 4);   // 16-lane broadcast
            float4 wv = latr[u];
            int k0 = seg * KSEG + u * 4;
            float v0 = q.x + wv.x;
            float v1 = q.y + wv.y;
            float v2 = q.z + wv.z;
            float v3 = q.w + wv.w;
            if (v0 > best) { best = v0; bidx = k0;     }
            if (v1 > best) { best = v1; bidx = k0 + 1; }
            if (v2 > best) { best = v2; bidx = k0 + 2; }
            if (v3 > best) { best = v3; bidx = k0 + 3; }
        }

        // ---- combine the wave's 4 segs per j via shfl (disjoint ascending k
        // ranges: tie -> smaller bidx == sequential first-max). No sync.
        {
            float ov = __shfl_xor(best, 16);
            int   oi = __shfl_xor(bidx, 16);
            if (ov > best || (ov == best && oi < bidx)) { best = ov; bidx = oi; }
            ov = __shfl_xor(best, 32);
            oi = __shfl_xor(bidx, 32);
            if (ov > best || (ov == best && oi < bidx)) { best = ov; bidx = oi; }
        }
        if ((tid & 63) < JPB) {                 // one lane per (wave, jj)
            smaxw[wav][jj] = best;
            sidxw[wav][jj] = (unsigned short)bidx;
        }
        __syncthreads();                        // barrier 2: partials visible

        // ---- final 4-deep combine (ascending wave == ascending seg) + publish
        if (tid < JPB) {
            float m = smaxw[0][tid];
            int  mi = sidxw[0][tid];
            #pragma unroll
            for (int ww = 1; ww < 4; ++ww) {
                float v = smaxw[ww][tid];
                if (v > m) { m = v; mi = sidxw[ww][tid]; }
            }
            int jw = j0 + tid;
            // reference quirk: j==0 forced from state 0; prevs[0] (staged by
            // tid 0 itself, program-ordered) is cols[t-1][0].
            float val = (jw == 0) ? (prevs[0] + lat00) : m;
            float out = val + esum_reg;         // one register add -- R3 chain
            AST((u32*)(cols + (size_t)t * NSTATES) + jw, __float_as_uint(out));
            bptr[(size_t)t * NSTATES + jw] = (unsigned short)mi;
        }

        // ---- issue next step's first sweep NOW (column t): its RTT hides
        // under the emis shadow below. ALD loads cannot sink past barrier 3.
        if (t + 1 < TT) {
            const u32* pn = (const u32*)(cols + (size_t)t * NSTATES) + tid * 4;
            pf0 = ALD(pn + 0); pf1 = ALD(pn + 1);
            pf2 = ALD(pn + 2); pf3 = ALD(pn + 3);
        }

        // ---- post-publish shadow: step t+1's emission slice + serial d-sum
        // (ascending d, bit-order identical to all passing rounds).
        if (t + 1 < TT) {
            emis(t + 1, (t + 1) & 1);
            __syncthreads();                    // barrier 3 (in shadow)
            if (tid < JPB) {
                float acc = 0.0f;
                #pragma unroll
                for (int d = 0; d < DD; ++d) acc += elp[(t + 1) & 1][tid][d];
                esum_reg = acc;
            }
        }
    }
}

// Parallel backtrace via segment transfer-map composition (verified R13-R15).
#define SEGR 64   // rows per segment; 64 segments x 64 rows = rows 0..4095
__global__ __launch_bounds__(256, 1) void k_backtrace(
    const float* __restrict__ lastcol, const unsigned short* __restrict__ bptr,
    int* __restrict__ seq, u32* __restrict__ ctrl,
    u32* __restrict__ entries, u32* __restrict__ maps)
{
    __shared__ unsigned short rows[SEGR][NSTATES];   // 128 KB
    __shared__ int s_last;
    const int tid = threadIdx.x;    // 256 threads
    const int s   = blockIdx.x;     // 64 segments
    const int lo  = (s == 0) ? 1 : s * SEGR;          // row 0 is never chased
    const int hi  = s * SEGR + SEGR - 1;              // s=63 -> 4095
    const int nrows = hi - lo + 1;

    // ---- stage rows lo..hi (coalesced uint4)
    for (int idx = tid; idx < nrows * 128; idx += 256) {
        int ro = idx >> 7, wo = idx & 127;
        ((uint4*)&rows[ro][0])[wo] =
            ((const uint4*)(bptr + (size_t)(lo + ro) * NSTATES))[wo];
    }
    __syncthreads();

    // ---- phase 1: 4 interleaved chases per thread over all staged rows
    int f0 = tid * 4, f1 = tid * 4 + 1, f2 = tid * 4 + 2, f3 = tid * 4 + 3;
    for (int r = hi; r >= lo; --r) {
        const unsigned short* row = &rows[r - lo][0];
        f0 = row[f0]; f1 = row[f1]; f2 = row[f2]; f3 = row[f3];
    }
    AST(maps + (size_t)s * 512 + 2 * tid,     (u32)f0 | ((u32)f1 << 16));
    AST(maps + (size_t)s * 512 + 2 * tid + 1, (u32)f2 | ((u32)f3 << 16));
    __syncthreads();                 // each wave drains vmcnt before barrier
    if (tid == 0)
        __hip_atomic_fetch_add(ctrl + 1, 1u, __ATOMIC_RELEASE,
                               __HIP_MEMORY_SCOPE_AGENT);

    // ---- phase 2 (block 0): argmax last column, compose maps, publish entries
    if (s == 0) {
        if (tid < 64) {
            float best = -__builtin_inff();
            int bi = 0;
            for (int n2 = tid; n2 < NSTATES; n2 += 64) {
                float v = lastcol[n2];
                if (v > best) { best = v; bi = n2; }
            }
            #pragma unroll
            for (int off = 32; off > 0; off >>= 1) {
                float ov = __shfl_xor(best, off);
                int   oi = __shfl_xor(bi, off);
                if (ov > best || (ov == best && oi < bi)) { best = ov; bi = oi; }
            }
            if (tid == 0) s_last = bi;
        }
        __syncthreads();
        if (tid == 0) {
            while (ALD(ctrl + 1) < 64u) __builtin_amdgcn_s_sleep(2);
            int last = s_last;
            seq[TT] = last; seq[TT - 1] = last;     // source appends twice
            u32 entry = (u32)last;
            for (int ss = 63; ss >= 1; --ss) {      // descending segment order
                AST(entries + ss, entry);
                u32 w = ALD(maps + (size_t)ss * 512 + (entry >> 1));
                entry = (entry & 1) ? (w >> 16) : (w & 0xFFFFu);
            }
            AST(entries + 0, entry);
            asm volatile("s_waitcnt vmcnt(0)" ::: "memory");  // entries first
            AST(ctrl + 2, 1u);                       // compose-done flag
        }
    }

    // ---- phase 3: replay own segment from its entry front (rows still in LDS)
    if (tid == 0) {
        while (ALD(ctrl + 2) == 0u) __builtin_amdgcn_s_sleep(2);
        u32 front = ALD(entries + s);
        for (int r = hi; r >= lo; --r) {
            front = rows[r - lo][front];
            seq[r - 1] = (int)front;
        }
    }
}

extern "C" void kernel_launch(void* const* d_in, const int* in_sizes, int n_in,
                              void* d_out, int out_size, void* d_ws, size_t ws_size,
                              hipStream_t stream) {
    const float* ev    = (const float*)d_in[0];   // [T, D]
    const float* prior = (const float*)d_in[1];   // [N]
    const float* tr    = (const float*)d_in[2];   // [N, N]
    const float* epar  = (const float*)d_in[3];   // [N, D, 2]
    int* seq = (int*)d_out;                       // [T+1]
    char* ws = (char*)d_ws;
    float* cols = (float*)(ws + OFF_COLS);
    unsigned short* bptr = (unsigned short*)(ws + OFF_PTR);
    u32* ctrl    = (u32*)ws;                      // [0]=fw ready [1]=maps [2]=flag
    u32* entries = (u32*)(ws + 256);
    u32* maps    = (u32*)(ws + 4096);

    hipMemsetAsync(ctrl, 0, 16, stream);          // zero control words
    k_forward<<<FW_BLOCKS, FW_THREADS, 0, stream>>>(tr, ev, epar, prior,
                                                    cols, bptr, ctrl);
    k_backtrace<<<64, 256, 0, stream>>>(cols + (size_t)(TT - 1) * NSTATES,
                                        bptr, seq, ctrl, entries, maps);
}

// Round 18
// 8181.624 us; speedup vs baseline: 1.2333x; 1.2333x over previous
//
#include <hip/hip_runtime.h>
#include <math.h>

#define NSTATES 1024
#define TT      4096
#define DD      20

#define FW_BLOCKS  64
#define FW_THREADS 256
#define JPB  16      // j per block   (FW_BLOCKS * JPB = NSTATES)
#define NSEG 16      // k segments    (JPB * NSEG = FW_THREADS)
#define KSEG 64      // k per segment (NSEG * KSEG = NSTATES)

#define SENT 0x7FC00000u   // canonical NaN: computed column values are never NaN

// workspace layout (bytes)
//   ws + 0      : ctrl[4]   (u32: [0]=fw ready, [1]=map count, [2]=compose flag)
//   ws + 256    : entries[64] (u32 per-segment entry front)
//   ws + 4096   : maps[64][512] (u32-packed u16 exit maps, 128 KB)
#define OFF_COLS  ((size_t)20 << 20)        // 16 MB per-step columns cols[t*N+j]
#define OFF_PTR   ((size_t)36 << 20)        // 8 MB  u16 backpointers, rows 1..T-1

typedef unsigned int u32;
typedef u32 u32x4 __attribute__((ext_vector_type(4)));

#define ALD(p) __hip_atomic_load((p), __ATOMIC_RELAXED, __HIP_MEMORY_SCOPE_AGENT)
#define AST(p, v) __hip_atomic_store((p), (v), __ATOMIC_RELAXED, __HIP_MEMORY_SCOPE_AGENT)

// Forward pass — the session-best verified configuration (R15: 8130 us
// dispatch, 1.985 us/step). Final composition of every verified win:
//   - R3:  lat VGPR-resident; padded LDS staging; shfl seg-combine
//   - R11: emission fused, computed in the post-publish shadow (distributed
//          over 256 threads; publisher d-sum off the critical chain)
//   - R12: sentinel-fill + logtrans fused into the prologue (2-dispatch graph)
//   - R14: poll de-atomized (one plain dwordx4 sc1 sweep + ALD fallback)
//   - R15: barrier 1 removed (stagers == readers per wave; lgkmcnt fence)
// Eight protocol attacks on the remaining handoff transit (R4/R5/R6/R8/R10/
// R14/R16/R17) regressed or were null: the residual ~4760cy/step is
// cross-XCD store-commit -> LLC -> 16K-poller detect transit (latency-bound;
// HBM 0.25%, VALU 7% -- no counter-visible resource left to trade).
__global__ __launch_bounds__(FW_THREADS, 1) void k_forward(
    const float* __restrict__ tr, const float* __restrict__ ev,
    const float* __restrict__ epar, const float* __restrict__ prior,
    float* __restrict__ cols, unsigned short* __restrict__ bptr,
    u32* __restrict__ ready)
{
    // padded [16][68]: row r holds words [r*64, r*64+64) of the prev column.
    __shared__ __align__(16) float prevs[NSEG * 68];
    __shared__ float          smaxw[4][JPB];   // per-wave partials (segs 4w..4w+3)
    __shared__ unsigned short sidxw[4][JPB];
    __shared__ float          elp[2][JPB][DD]; // double-buffered emission log-p
    const int tid  = threadIdx.x;
    const int seg  = tid >> 4;                  // 0..15: k in [seg*64, seg*64+64)
    const int jj   = tid & (JPB - 1);
    const int wav  = tid >> 6;                  // wave id 0..3 (holds segs 4w..4w+3)
    const int j0   = blockIdx.x * JPB;
    const int j    = j0 + jj;

    // ---- prologue A: sentinel-fill this block's slice of cols (256 KB)
    {
        uint4* mine = (uint4*)cols + (size_t)blockIdx.x * (NSTATES * TT / 4 / FW_BLOCKS);
        const uint4 sv = make_uint4(SENT, SENT, SENT, SENT);
        #pragma unroll
        for (int i = 0; i < (NSTATES * TT / 4 / FW_BLOCKS) / FW_THREADS; ++i)
            mine[i * FW_THREADS + tid] = sv;
    }

    // ---- prologue B: lat slice direct from tr (bit-identical to k_logtrans:
    // same logf on the same tr element). lat[j*N+k] = logf(tr[k*N+j]).
    const float lat00 = logf(tr[0]);            // log trans[0][0] (j==0 quirk)
    float4 latr[16];
    #pragma unroll
    for (int u = 0; u < 16; ++u) {
        #pragma unroll
        for (int i = 0; i < 4; ++i) {
            int k = seg * KSEG + u * 4 + i;
            ((float*)&latr[u])[i] = logf(tr[(size_t)k * NSTATES + j]);
        }
    }

    // ---- distributed-emission constants (items: it0 = tid, it1 = tid+256);
    // item -> (jj_e = item/20, d_e = item%20); 320 items cover 16j x 20d.
    const int jj0e = tid / DD, d0e = tid % DD;
    const float m0 = epar[((size_t)(j0 + jj0e) * DD + d0e) * 2 + 0];
    const float s0 = epar[((size_t)(j0 + jj0e) * DD + d0e) * 2 + 1];
    const float coef0 = 1.0f / sqrtf(6.2831853071795864769f * s0);
    const float den0  = 2.0f * (s0 * s0);
    const bool  has1  = (tid + 256) < JPB * DD;     // tid < 64
    const int   it1   = tid + 256;
    const int jj1e = has1 ? it1 / DD : 0, d1e = has1 ? it1 % DD : 0;
    const float m1 = has1 ? epar[((size_t)(j0 + jj1e) * DD + d1e) * 2 + 0] : 0.0f;
    const float s1 = has1 ? epar[((size_t)(j0 + jj1e) * DD + d1e) * 2 + 1] : 1.0f;
    const float coef1 = 1.0f / sqrtf(6.2831853071795864769f * s1);
    const float den1  = 2.0f * (s1 * s1);

    // faithful to reference: p = coef * expf(-num/den); logp = logf(p).
    // -inf (underflow) propagates; never NaN. Verbatim from the verified k_emis.
    auto emis = [&](int t, int buf) {
        float x0  = ev[(size_t)t * DD + d0e];
        float df0 = x0 - m0;
        float num0 = df0 * df0;
        float p0  = coef0 * expf(-num0 / den0);
        elp[buf][jj0e][d0e] = logf(p0);
        if (has1) {
            float x1  = ev[(size_t)t * DD + d1e];
            float df1 = x1 - m1;
            float num1 = df1 * df1;
            float p1  = coef1 * expf(-num1 / den1);
            elp[buf][jj1e][d1e] = logf(p1);
        }
    };

    // ---- prologue C: grid-ready barrier (fill visible -> count -> spin)
    __syncthreads();                            // block's fill issued by all
    if (tid == 0) {
        asm volatile("s_waitcnt vmcnt(0)" ::: "memory");   // fill visible first
        __hip_atomic_fetch_add(ready, 1u, __ATOMIC_RELEASE,
                               __HIP_MEMORY_SCOPE_AGENT);
        while (ALD(ready) < (u32)FW_BLOCKS) __builtin_amdgcn_s_sleep(2);
    }
    __syncthreads();                            // whole grid sentinel-ready

    // thread stages its 4 polled words at padded (row tid>>4, col (tid&15)*4)
    float* dstp = &prevs[(tid >> 4) * 68 + (tid & 15) * 4];
    const float* rowp = &prevs[seg * 68];

    // ---- prologue D: col0 (t=0) and the pipelined esum for t=1 ----
    emis(0, 0);
    __syncthreads();
    if (tid < JPB) {
        float acc = 0.0f;
        #pragma unroll
        for (int d = 0; d < DD; ++d) acc += elp[0][tid][d];   // ascending d
        float c0 = logf(prior[j0 + tid]) + acc;
        AST((u32*)cols + (j0 + tid), __float_as_uint(c0));
    }
    __syncthreads();                            // col0 sum read before buf reuse
    emis(1, 1);
    __syncthreads();
    float esum_reg = 0.0f;
    if (tid < JPB) {
        #pragma unroll
        for (int d = 0; d < DD; ++d) esum_reg += elp[1][tid][d];   // ascending d
    }

    for (int t = 1; t < TT; ++t) {
        // ---- poll previous column: ONE plain dwordx4 sc1 sweep per thread
        // (R14, proven), s_sleep backoff, 32-try ALD fallback for hang-safety.
        const u32* p = (const u32*)(cols + (size_t)(t - 1) * NSTATES) + tid * 4;
        u32x4 A;
        int tries = 0;
        for (;;) {
            asm volatile(
                "global_load_dwordx4 %0, %1, off sc1\n\t"
                "s_waitcnt vmcnt(0)"
                : "=&v"(A) : "v"(p) : "memory");
            if (A.x != SENT && A.y != SENT && A.z != SENT && A.w != SENT) break;
            if (++tries >= 32) {
                u32 a0 = ALD(p + 0), a1 = ALD(p + 1), a2 = ALD(p + 2), a3 = ALD(p + 3);
                if (a0 != SENT && a1 != SENT && a2 != SENT && a3 != SENT) {
                    A.x = a0; A.y = a1; A.z = a2; A.w = a3;
                    break;
                }
                tries = 0;
            }
            __builtin_amdgcn_s_sleep(1);
        }
        {
            float4 v;
            v.x = __uint_as_float(A.x);
            v.y = __uint_as_float(A.y);
            v.z = __uint_as_float(A.z);
            v.w = __uint_as_float(A.w);
            *(float4*)dstp = v;                 // padded b128 store, conflict-free
        }
        // barrier 1 removed (R15): row r's stagers == row r's readers (same
        // wave); same-wave LDS pipe is in-order. Fence stops compiler hoisting
        // the dependent ds_reads above the staging write (rule #18).
        asm volatile("s_waitcnt lgkmcnt(0)" ::: "memory");
        __builtin_amdgcn_sched_barrier(0);

        // ---- scan this thread's 64 k's for its j: first-max (strict >, asc k)
        float best = -__builtin_inff();
        int bidx = seg * KSEG;
        #pragma unroll
        for (int u = 0; u < 16; ++u) {
            float4 q  = *(const float4*)(rowp + u * 4);   // 16-lane broadcast
            float4 wv = latr[u];
            int k0 = seg * KSEG + u * 4;
            float v0 = q.x + wv.x;
            float v1 = q.y + wv.y;
            float v2 = q.z + wv.z;
            float v3 = q.w + wv.w;
            if (v0 > best) { best = v0; bidx = k0;     }
            if (v1 > best) { best = v1; bidx = k0 + 1; }
            if (v2 > best) { best = v2; bidx = k0 + 2; }
            if (v3 > best) { best = v3; bidx = k0 + 3; }
        }

        // ---- combine the wave's 4 segs per j via shfl (disjoint ascending k
        // ranges: tie -> smaller bidx == sequential first-max). No sync.
        {
            float ov = __shfl_xor(best, 16);
            int   oi = __shfl_xor(bidx, 16);
            if (ov > best || (ov == best && oi < bidx)) { best = ov; bidx = oi; }
            ov = __shfl_xor(best, 32);
            oi = __shfl_xor(bidx, 32);
            if (ov > best || (ov == best && oi < bidx)) { best = ov; bidx = oi; }
        }
        if ((tid & 63) < JPB) {                 // one lane per (wave, jj)
            smaxw[wav][jj] = best;
            sidxw[wav][jj] = (unsigned short)bidx;
        }
        __syncthreads();                        // barrier 2: partials visible

        // ---- final 4-deep combine (ascending wave == ascending seg) + publish
        if (tid < JPB) {
            float m = smaxw[0][tid];
            int  mi = sidxw[0][tid];
            #pragma unroll
            for (int ww = 1; ww < 4; ++ww) {
                float v = smaxw[ww][tid];
                if (v > m) { m = v; mi = sidxw[ww][tid]; }
            }
            int jw = j0 + tid;
            // reference quirk: j==0 forced from state 0; prevs[0] (staged by
            // tid 0 itself, program-ordered) is cols[t-1][0].
            float val = (jw == 0) ? (prevs[0] + lat00) : m;
            float out = val + esum_reg;         // one register add -- R3 chain
            AST((u32*)(cols + (size_t)t * NSTATES) + jw, __float_as_uint(out));
            bptr[(size_t)t * NSTATES + jw] = (unsigned short)mi;
        }

        // ---- post-publish shadow: step t+1's emission slice + serial d-sum
        // (ascending d, bit-order identical to all passing rounds).
        if (t + 1 < TT) {
            emis(t + 1, (t + 1) & 1);
            __syncthreads();                    // barrier 3 (in shadow)
            if (tid < JPB) {
                float acc = 0.0f;
                #pragma unroll
                for (int d = 0; d < DD; ++d) acc += elp[(t + 1) & 1][tid][d];
                esum_reg = acc;
            }
        }
    }
}

// Parallel backtrace via segment transfer-map composition (verified R13-R15).
#define SEGR 64   // rows per segment; 64 segments x 64 rows = rows 0..4095
__global__ __launch_bounds__(256, 1) void k_backtrace(
    const float* __restrict__ lastcol, const unsigned short* __restrict__ bptr,
    int* __restrict__ seq, u32* __restrict__ ctrl,
    u32* __restrict__ entries, u32* __restrict__ maps)
{
    __shared__ unsigned short rows[SEGR][NSTATES];   // 128 KB
    __shared__ int s_last;
    const int tid = threadIdx.x;    // 256 threads
    const int s   = blockIdx.x;     // 64 segments
    const int lo  = (s == 0) ? 1 : s * SEGR;          // row 0 is never chased
    const int hi  = s * SEGR + SEGR - 1;              // s=63 -> 4095
    const int nrows = hi - lo + 1;

    // ---- stage rows lo..hi (coalesced uint4)
    for (int idx = tid; idx < nrows * 128; idx += 256) {
        int ro = idx >> 7, wo = idx & 127;
        ((uint4*)&rows[ro][0])[wo] =
            ((const uint4*)(bptr + (size_t)(lo + ro) * NSTATES))[wo];
    }
    __syncthreads();

    // ---- phase 1: 4 interleaved chases per thread over all staged rows
    int f0 = tid * 4, f1 = tid * 4 + 1, f2 = tid * 4 + 2, f3 = tid * 4 + 3;
    for (int r = hi; r >= lo; --r) {
        const unsigned short* row = &rows[r - lo][0];
        f0 = row[f0]; f1 = row[f1]; f2 = row[f2]; f3 = row[f3];
    }
    AST(maps + (size_t)s * 512 + 2 * tid,     (u32)f0 | ((u32)f1 << 16));
    AST(maps + (size_t)s * 512 + 2 * tid + 1, (u32)f2 | ((u32)f3 << 16));
    __syncthreads();                 // each wave drains vmcnt before barrier
    if (tid == 0)
        __hip_atomic_fetch_add(ctrl + 1, 1u, __ATOMIC_RELEASE,
                               __HIP_MEMORY_SCOPE_AGENT);

    // ---- phase 2 (block 0): argmax last column, compose maps, publish entries
    if (s == 0) {
        if (tid < 64) {
            float best = -__builtin_inff();
            int bi = 0;
            for (int n2 = tid; n2 < NSTATES; n2 += 64) {
                float v = lastcol[n2];
                if (v > best) { best = v; bi = n2; }
            }
            #pragma unroll
            for (int off = 32; off > 0; off >>= 1) {
                float ov = __shfl_xor(best, off);
                int   oi = __shfl_xor(bi, off);
                if (ov > best || (ov == best && oi < bi)) { best = ov; bi = oi; }
            }
            if (tid == 0) s_last = bi;
        }
        __syncthreads();
        if (tid == 0) {
            while (ALD(ctrl + 1) < 64u) __builtin_amdgcn_s_sleep(2);
            int last = s_last;
            seq[TT] = last; seq[TT - 1] = last;     // source appends twice
            u32 entry = (u32)last;
            for (int ss = 63; ss >= 1; --ss) {      // descending segment order
                AST(entries + ss, entry);
                u32 w = ALD(maps + (size_t)ss * 512 + (entry >> 1));
                entry = (entry & 1) ? (w >> 16) : (w & 0xFFFFu);
            }
            AST(entries + 0, entry);
            asm volatile("s_waitcnt vmcnt(0)" ::: "memory");  // entries first
            AST(ctrl + 2, 1u);                       // compose-done flag
        }
    }

    // ---- phase 3: replay own segment from its entry front (rows still in LDS)
    if (tid == 0) {
        while (ALD(ctrl + 2) == 0u) __builtin_amdgcn_s_sleep(2);
        u32 front = ALD(entries + s);
        for (int r = hi; r >= lo; --r) {
            front = rows[r - lo][front];
            seq[r - 1] = (int)front;
        }
    }
}

extern "C" void kernel_launch(void* const* d_in, const int* in_sizes, int n_in,
                              void* d_out, int out_size, void* d_ws, size_t ws_size,
                              hipStream_t stream) {
    const float* ev    = (const float*)d_in[0];   // [T, D]
    const float* prior = (const float*)d_in[1];   // [N]
    const float* tr    = (const float*)d_in[2];   // [N, N]
    const float* epar  = (const float*)d_in[3];   // [N, D, 2]
    int* seq = (int*)d_out;                       // [T+1]
    char* ws = (char*)d_ws;
    float* cols = (float*)(ws + OFF_COLS);
    unsigned short* bptr = (unsigned short*)(ws + OFF_PTR);
    u32* ctrl    = (u32*)ws;                      // [0]=fw ready [1]=maps [2]=flag
    u32* entries = (u32*)(ws + 256);
    u32* maps    = (u32*)(ws + 4096);

    hipMemsetAsync(ctrl, 0, 16, stream);          // zero control words
    k_forward<<<FW_BLOCKS, FW_THREADS, 0, stream>>>(tr, ev, epar, prior,
                                                    cols, bptr, ctrl);
    k_backtrace<<<64, 256, 0, stream>>>(cols + (size_t)(TT - 1) * NSTATES,
                                        bptr, seq, ctrl, entries, maps);
}